// Round 6
// baseline (2095.810 us; speedup 1.0000x reference)
//
#include <hip/hip_runtime.h>
#include <cstdint>
#include <cstddef>

// Problem constants (reference: N=4, P1=P2=2048, D=64, eps=0.1, 50 iters)
#define NB 4
#define P1 2048
#define P2 2048
#define DD 64
#define ITER 50
#define EPS 0.1f
#define INV_EPS 10.0f          // 1.0f/0.1f rounds to exactly 10.0f
#define THRESH 0.1f
// log(1/2048 + 1e-8) in fp32
#define LOG_MU -7.6245985f
#define ELOG (-0.76245985f)    // EPS * LOG_MU (== EPS * LOG_NU)
#define MU_VAL 0.00048829125f  // exp(LOG_MU) = 1/2048 + 1e-8
#define ERRSLOTS 32
#define RP (P2 / 4)            // float4s per row
#define PCHUNKS 128            // iter blocks per batch (16 rows each)

// ---------------------------------------------------------------------------
// prep0 (grid-strided): S = M + M^T, zero errAcc + Z, init active/cost.
// ---------------------------------------------------------------------------
__global__ void prep0(const float* __restrict__ M, float* __restrict__ S,
                      float* __restrict__ errAcc, int* __restrict__ active,
                      float* __restrict__ cost, float* __restrict__ Zb) {
    int tid = blockIdx.x * 256 + threadIdx.x;
    int stride = gridDim.x * 256;
    for (int k = tid; k < DD * DD; k += stride) {
        int d = k >> 6, e = k & 63;
        S[k] = M[d * DD + e] + M[e * DD + d];
    }
    for (int k = tid; k < ITER * ERRSLOTS; k += stride) errAcc[k] = 0.0f;
    for (int k = tid; k < ITER * NB * P2; k += stride) Zb[k] = 0.0f;
    if (tid < 64) active[tid] = (tid == 0) ? 1 : 0;
    if (tid < NB) cost[tid] = 0.0f;
}

// ---------------------------------------------------------------------------
// prep1: one wave per row. x-rows: xS = x@S, dx = 0.5*x·(Sx), u=0.
//        y-rows: dy = 0.5*y·(Sy), v=0.
// ---------------------------------------------------------------------------
__global__ __launch_bounds__(256) void prep1(const float* __restrict__ x,
                                             const float* __restrict__ y,
                                             const float* __restrict__ S,
                                             float* __restrict__ xS,
                                             float* __restrict__ dx,
                                             float* __restrict__ dy,
                                             float* __restrict__ u,
                                             float* __restrict__ v) {
    __shared__ float Sl[DD * DD];
    int t = threadIdx.x;
    for (int k = t; k < DD * DD; k += 256) Sl[k] = S[k];
    __syncthreads();
    int wave = t >> 6, lane = t & 63;
    int r = blockIdx.x * 4 + wave;          // 0 .. N*(P1+P2)-1
    bool isX = r < NB * P1;
    const float* src = isX ? x : y;
    int rr = isX ? r : r - NB * P1;
    float xv = src[(size_t)rr * DD + lane];
    float acc = 0.0f;
    #pragma unroll
    for (int d = 0; d < DD; ++d) {
        float xd = __shfl(xv, d, 64);
        acc = fmaf(xd, Sl[d * DD + lane], acc);
    }
    float p = acc * xv;
    #pragma unroll
    for (int o = 32; o; o >>= 1) p += __shfl_xor(p, o, 64);
    if (isX) {
        xS[(size_t)rr * DD + lane] = acc;
        if (lane == 0) { dx[rr] = 0.5f * p; u[rr] = 0.0f; }
    } else {
        if (lane == 0) { dy[rr] = 0.5f * p; v[rr] = 0.0f; }
    }
}

// ---------------------------------------------------------------------------
// gemmC: C[n,i,j] = dx[n,i] + dy[n,j] - sum_e xS[n,i,e]*y[n,j,e]
// ---------------------------------------------------------------------------
__global__ __launch_bounds__(256) void gemmC(const float* __restrict__ xS,
                                             const float* __restrict__ y,
                                             const float* __restrict__ dx,
                                             const float* __restrict__ dy,
                                             float* __restrict__ C) {
    __shared__ float xs[64][68];
    __shared__ float ys[64][68];
    int n = blockIdx.z;
    int i0 = blockIdx.y * 64, j0 = blockIdx.x * 64;
    int t = threadIdx.x;

    #pragma unroll
    for (int k = 0; k < 4; ++k) {
        int f = t + 256 * k;       // 0..1023
        int row = f >> 4;          // 0..63
        int c4 = f & 15;           // 0..15
        float4 a = ((const float4*)xS)[((size_t)(n * P1 + i0 + row)) * (DD / 4) + c4];
        xs[4 * c4 + 0][row] = a.x; xs[4 * c4 + 1][row] = a.y;
        xs[4 * c4 + 2][row] = a.z; xs[4 * c4 + 3][row] = a.w;
        float4 b = ((const float4*)y)[((size_t)(n * P2 + j0 + row)) * (DD / 4) + c4];
        ys[4 * c4 + 0][row] = b.x; ys[4 * c4 + 1][row] = b.y;
        ys[4 * c4 + 2][row] = b.z; ys[4 * c4 + 3][row] = b.w;
    }
    __syncthreads();

    int tx = t & 15, ty = t >> 4;
    float acc[4][4] = {};
    #pragma unroll
    for (int e = 0; e < 64; ++e) {
        float4 a = *(const float4*)&xs[e][4 * ty];
        float4 b = *(const float4*)&ys[e][4 * tx];
        acc[0][0] = fmaf(a.x, b.x, acc[0][0]); acc[0][1] = fmaf(a.x, b.y, acc[0][1]);
        acc[0][2] = fmaf(a.x, b.z, acc[0][2]); acc[0][3] = fmaf(a.x, b.w, acc[0][3]);
        acc[1][0] = fmaf(a.y, b.x, acc[1][0]); acc[1][1] = fmaf(a.y, b.y, acc[1][1]);
        acc[1][2] = fmaf(a.y, b.z, acc[1][2]); acc[1][3] = fmaf(a.y, b.w, acc[1][3]);
        acc[2][0] = fmaf(a.z, b.x, acc[2][0]); acc[2][1] = fmaf(a.z, b.y, acc[2][1]);
        acc[2][2] = fmaf(a.z, b.z, acc[2][2]); acc[2][3] = fmaf(a.z, b.w, acc[2][3]);
        acc[3][0] = fmaf(a.w, b.x, acc[3][0]); acc[3][1] = fmaf(a.w, b.y, acc[3][1]);
        acc[3][2] = fmaf(a.w, b.z, acc[3][2]); acc[3][3] = fmaf(a.w, b.w, acc[3][3]);
    }

    int iBase = i0 + ty * 4, jBase = j0 + tx * 4;
    float4 dy4 = *(const float4*)&dy[n * P2 + jBase];
    #pragma unroll
    for (int r = 0; r < 4; ++r) {
        float dxv = dx[n * P1 + iBase + r];
        float4 o;
        o.x = dxv + dy4.x - acc[r][0];
        o.y = dxv + dy4.y - acc[r][1];
        o.z = dxv + dy4.z - acc[r][2];
        o.w = dxv + dy4.w - acc[r][3];
        *(float4*)&C[((size_t)(n * P1 + iBase + r)) * P2 + jBase] = o;
    }
}

// ---------------------------------------------------------------------------
// Row helpers (r4-validated)
// ---------------------------------------------------------------------------
__device__ __forceinline__ void load_row8(float4 dst[8], const float4* base, int lane) {
    #pragma unroll
    for (int k = 0; k < 8; ++k) dst[k] = base[lane + 64 * k];
}

// Transforms c in place to q = (ai - C) + b; returns eps*LSE_j(q_j/eps).
__device__ __forceinline__ float row_lse(float4 c[8], float ai, const float* bl, int lane) {
    float m = -3.4e38f;
    #pragma unroll
    for (int k = 0; k < 8; ++k) {
        float4 vv = ((const float4*)bl)[lane + 64 * k];
        c[k].x = (ai - c[k].x) + vv.x;
        c[k].y = (ai - c[k].y) + vv.y;
        c[k].z = (ai - c[k].z) + vv.z;
        c[k].w = (ai - c[k].w) + vv.w;
        m = fmaxf(m, fmaxf(fmaxf(c[k].x, c[k].y), fmaxf(c[k].z, c[k].w)));
    }
    #pragma unroll
    for (int o = 1; o < 64; o <<= 1) m = fmaxf(m, __shfl_xor(m, o, 64));
    float s = 0.0f;
    #pragma unroll
    for (int k = 0; k < 8; ++k)
        s += __expf((c[k].x - m) * INV_EPS) + __expf((c[k].y - m) * INV_EPS) +
             __expf((c[k].z - m) * INV_EPS) + __expf((c[k].w - m) * INV_EPS);
    #pragma unroll
    for (int o = 1; o < 64; o <<= 1) s += __shfl_xor(s, o, 64);
    return EPS * __logf(s) + m;
}

// Online (m,s) merge of one scalar term q (values in C-units, exp scaled by 1/eps)
__device__ __forceinline__ void mergec(float& m, float& s, float q) {
    float nm = fmaxf(m, q);
    s = s * __expf((m - nm) * INV_EPS) + __expf((q - nm) * INV_EPS);
    m = nm;
}
__device__ __forceinline__ void mergems(float& m, float& s, float mo, float so) {
    float nm = fmaxf(m, mo);
    s = s * __expf((m - nm) * INV_EPS) + so * __expf((mo - nm) * INV_EPS);
    m = nm;
}
__device__ __forceinline__ void merge44(float4& m, float4& s, float4 mo, float4 so) {
    mergems(m.x, s.x, mo.x, so.x);
    mergems(m.y, s.y, mo.y, so.y);
    mergems(m.z, s.z, mo.z, so.z);
    mergems(m.w, s.w, mo.w, so.w);
}

// Merge row's q (+wave-uniform dr = u_new - u_old) into per-column (M,S) regs.
__device__ __forceinline__ void merge_row(float4 M[8], float4 S[8],
                                          const float4 q[8], float dr) {
    #pragma unroll
    for (int k = 0; k < 8; ++k) {
        mergec(M[k].x, S[k].x, q[k].x + dr);
        mergec(M[k].y, S[k].y, q[k].y + dr);
        mergec(M[k].z, S[k].z, q[k].z + dr);
        mergec(M[k].w, S[k].w, q[k].w + dr);
    }
}

// ---------------------------------------------------------------------------
// iter_pass (max-safe, t=0 only — q=-C unbounded): full Sinkhorn u-update
// plus in-register per-column (m,s) partials. 16 rows/block, 512 blocks.
// ---------------------------------------------------------------------------
__global__ __launch_bounds__(256) void iter_pass(const float* __restrict__ C,
                                                 float* __restrict__ u,
                                                 const float* __restrict__ v,
                                                 float* __restrict__ pm,
                                                 float* __restrict__ ps,
                                                 float* __restrict__ errAcc,
                                                 const int* __restrict__ active,
                                                 int t_iter) {
    if (!active[t_iter]) return;
    __shared__ float bl[P2];          // 8 KB: v values for this batch
    __shared__ float4 LM[4][512];     // 32 KB: per-wave column maxima
    __shared__ float4 LS[4][512];     // 32 KB: per-wave column sums
    __shared__ float da_s[4];
    int t = threadIdx.x;
    int n = blockIdx.x >> 7;                       // PCHUNKS=128 blocks/batch
    int i0 = (blockIdx.x & (PCHUNKS - 1)) * 16;
    {
        const float4* bsrc = (const float4*)(v + n * P2);
        ((float4*)bl)[t] = bsrc[t];
        ((float4*)bl)[t + 256] = bsrc[t + 256];
    }
    __syncthreads();

    int wave = t >> 6, lane = t & 63;
    int irow = i0 + wave * 4;
    float* arow = u + n * P1 + irow;
    float a0 = arow[0], a1 = arow[1], a2 = arow[2], a3 = arow[3];
    const float4* base = (const float4*)(C + ((size_t)(n * P1 + irow)) * P2);

    float4 M[8], S[8];
    #pragma unroll
    for (int k = 0; k < 8; ++k) {
        M[k] = make_float4(-3.4e38f, -3.4e38f, -3.4e38f, -3.4e38f);
        S[k] = make_float4(0.0f, 0.0f, 0.0f, 0.0f);
    }

    float4 A[8], B[8];
    load_row8(A, base, lane);
    load_row8(B, base + RP, lane);
    float l0 = row_lse(A, a0, bl, lane);
    float d0 = ELOG - l0;
    merge_row(M, S, A, d0);
    load_row8(A, base + 2 * RP, lane);
    float l1 = row_lse(B, a1, bl, lane);
    float d1 = ELOG - l1;
    merge_row(M, S, B, d1);
    load_row8(B, base + 3 * RP, lane);
    float l2 = row_lse(A, a2, bl, lane);
    float d2 = ELOG - l2;
    merge_row(M, S, A, d2);
    float l3 = row_lse(B, a3, bl, lane);
    float d3 = ELOG - l3;
    merge_row(M, S, B, d3);

    if (lane == 0) {
        arow[0] = a0 + d0; arow[1] = a1 + d1;
        arow[2] = a2 + d2; arow[3] = a3 + d3;
        da_s[wave] = fabsf(d0) + fabsf(d1) + fabsf(d2) + fabsf(d3);
    }

    // cross-wave column merge through LDS
    #pragma unroll
    for (int k = 0; k < 8; ++k) {
        LM[wave][lane + 64 * k] = M[k];
        LS[wave][lane + 64 * k] = S[k];
    }
    __syncthreads();

    float4* pm4 = (float4*)pm;
    float4* ps4 = (float4*)ps;
    size_t pb4 = (size_t)blockIdx.x * 512;
    #pragma unroll
    for (int sl = 0; sl < 2; ++sl) {
        int slot = t + 256 * sl;
        float4 m = LM[0][slot], s = LS[0][slot];
        merge44(m, s, LM[1][slot], LS[1][slot]);
        merge44(m, s, LM[2][slot], LS[2][slot]);
        merge44(m, s, LM[3][slot], LS[3][slot]);
        pm4[pb4 + slot] = m;
        ps4[pb4 + slot] = s;
    }

    if (t == 0) {
        atomicAdd(&errAcc[t_iter * ERRSLOTS + (blockIdx.x & (ERRSLOTS - 1))],
                  da_s[0] + da_s[1] + da_s[2] + da_s[3]);
    }
}

// ---------------------------------------------------------------------------
// v_comb (t=0 only): merge PCHUNKS (m,s) partials per column, apply v update,
// advance active[1] (exact gate from err_0).
// ---------------------------------------------------------------------------
__global__ __launch_bounds__(256) void v_comb(const float* __restrict__ pm,
                                              const float* __restrict__ ps,
                                              float* __restrict__ v,
                                              const float* __restrict__ errAcc,
                                              int* __restrict__ active,
                                              int t_iter) {
    if (blockIdx.x == 0 && threadIdx.x == 0) {
        float e = 0.0f;
        #pragma unroll
        for (int q = 0; q < ERRSLOTS; ++q) e += errAcc[t_iter * ERRSLOTS + q];
        if (active[t_iter] && (e * 0.25f >= THRESH)) active[t_iter + 1] = 1;
    }
    if (!active[t_iter]) return;
    __shared__ float LMv[4][64];
    __shared__ float LSv[4][64];
    int t = threadIdx.x, wave = t >> 6, lane = t & 63;
    int n = blockIdx.x >> 5;
    int j = ((blockIdx.x & 31) << 6) + lane;
    const float* pmb = pm + ((size_t)(n * PCHUNKS + wave * 32)) * P2 + j;
    const float* psb = ps + ((size_t)(n * PCHUNKS + wave * 32)) * P2 + j;
    float m0 = -3.4e38f, s0 = 0.0f, m1 = -3.4e38f, s1 = 0.0f;
    float m2 = -3.4e38f, s2 = 0.0f, m3 = -3.4e38f, s3 = 0.0f;
    #pragma unroll
    for (int c = 0; c < 32; c += 4) {
        mergems(m0, s0, pmb[(size_t)(c + 0) * P2], psb[(size_t)(c + 0) * P2]);
        mergems(m1, s1, pmb[(size_t)(c + 1) * P2], psb[(size_t)(c + 1) * P2]);
        mergems(m2, s2, pmb[(size_t)(c + 2) * P2], psb[(size_t)(c + 2) * P2]);
        mergems(m3, s3, pmb[(size_t)(c + 3) * P2], psb[(size_t)(c + 3) * P2]);
    }
    mergems(m0, s0, m1, s1);
    mergems(m2, s2, m3, s3);
    mergems(m0, s0, m2, s2);
    LMv[wave][lane] = m0; LSv[wave][lane] = s0;
    __syncthreads();
    if (wave == 0) {
        float m = LMv[0][lane], s = LSv[0][lane];
        mergems(m, s, LMv[1][lane], LSv[1][lane]);
        mergems(m, s, LMv[2][lane], LSv[2][lane]);
        mergems(m, s, LMv[3][lane], LSv[3][lane]);
        float lse = EPS * __logf(s) + m;
        v[n * P2 + j] = v[n * P2 + j] + ELOG - lse;
    }
}

// ---------------------------------------------------------------------------
// FAST PATH (t >= 1), FUSED. Invariant (r5-validated): after iteration 0's
// full (u,v) update, every exp((u-C+v)/eps) <= MU and row/col sums live in
// [2.4e-7, 4.4e6] -> plain fp32 sums, no max tracking.
//
// Fusion scheme (removes v_fast + its 4.2MB partial round-trip):
//  - K_t's epilogue atomically adds its per-column partials into Z[t] (8KB
//    per batch, pre-zeroed by prep0; fire-and-forget).
//  - K_t's prologue (t>=2) recomputes v_{t-1} = v_{t-2} + ELOG - eps*log(Z[t-1])
//    for all 2048 columns (16KB reads + 8 logs/thread); block (bid&127)==0
//    writes v_{t-1} to the parity buffer for K_{t+1}. v double-buffered
//    (v=buf0, v2=buf1) so prologue reads and writer writes never alias.
//  - active gate lags one iteration (block 0 of K_t sets active[t+1] from
//    errAcc[t-1]); if the early-stop ever trips we run one extra step whose
//    drift (err<0.1 over 2048 rows) is ~1e-4 in potentials — far under tol.
// 16 rows/block, 512 blocks (1024-block variants measured 2x WORSE, r3/r5).
// ---------------------------------------------------------------------------
__device__ __forceinline__ float row_sum(float4 c[8], float aiv, const float* bl,
                                         int lane) {
    float s = 0.0f;
    #pragma unroll
    for (int k = 0; k < 8; ++k) {
        float4 vv = ((const float4*)bl)[lane + 64 * k];
        c[k].x = __expf(fmaf(c[k].x, -INV_EPS, aiv + vv.x));
        c[k].y = __expf(fmaf(c[k].y, -INV_EPS, aiv + vv.y));
        c[k].z = __expf(fmaf(c[k].z, -INV_EPS, aiv + vv.z));
        c[k].w = __expf(fmaf(c[k].w, -INV_EPS, aiv + vv.w));
        s += (c[k].x + c[k].y) + (c[k].z + c[k].w);
    }
    #pragma unroll
    for (int o = 1; o < 64; o <<= 1) s += __shfl_xor(s, o, 64);
    return s;
}

__device__ __forceinline__ void acc_row(float4 S[8], const float4 q[8], float ed) {
    #pragma unroll
    for (int k = 0; k < 8; ++k) {
        S[k].x = fmaf(q[k].x, ed, S[k].x);
        S[k].y = fmaf(q[k].y, ed, S[k].y);
        S[k].z = fmaf(q[k].z, ed, S[k].z);
        S[k].w = fmaf(q[k].w, ed, S[k].w);
    }
}

__global__ __launch_bounds__(256) void iter_fused(const float* __restrict__ C,
                                                  float* __restrict__ u,
                                                  float* __restrict__ vb0,
                                                  float* __restrict__ vb1,
                                                  float* __restrict__ Zb,
                                                  float* __restrict__ errAcc,
                                                  int* __restrict__ active,
                                                  int t_iter) {
    if (!active[t_iter]) return;
    __shared__ float bl[P2];          // 8 KB: v_{t-1}*INV_EPS for this batch
    __shared__ float4 LS[4][512];     // 32 KB: per-wave column sums
    __shared__ float da_s[4];
    int t = threadIdx.x;
    int n = blockIdx.x >> 7;
    int i0 = (blockIdx.x & (PCHUNKS - 1)) * 16;

    // lagged active gate: err from K_{t-1} (complete: stream-ordered)
    if (blockIdx.x == 0 && t == 0) {
        float e = 0.0f;
        #pragma unroll
        for (int q = 0; q < ERRSLOTS; ++q) e += errAcc[(t_iter - 1) * ERRSLOTS + q];
        if (e * 0.25f >= THRESH) active[t_iter + 1] = 1;
    }

    // prologue: build bl = v_{t-1} * INV_EPS
    {
        float4 vn0, vn1;
        if (t_iter == 1) {
            const float4* v04 = (const float4*)(vb0 + n * P2);
            vn0 = v04[t]; vn1 = v04[t + 256];
        } else {
            const float* vp = (t_iter & 1) ? vb1 : vb0;      // buf[(t-2)&1]
            float* vw = (t_iter & 1) ? vb0 : vb1;            // buf[(t-1)&1]
            const float4* vp4 = (const float4*)(vp + n * P2);
            const float4* zp4 = (const float4*)(Zb + ((size_t)(t_iter - 1) * NB + n) * P2);
            float4 a0 = vp4[t], a1 = vp4[t + 256];
            float4 z0 = zp4[t], z1 = zp4[t + 256];
            vn0.x = a0.x + (ELOG - EPS * __logf(z0.x));
            vn0.y = a0.y + (ELOG - EPS * __logf(z0.y));
            vn0.z = a0.z + (ELOG - EPS * __logf(z0.z));
            vn0.w = a0.w + (ELOG - EPS * __logf(z0.w));
            vn1.x = a1.x + (ELOG - EPS * __logf(z1.x));
            vn1.y = a1.y + (ELOG - EPS * __logf(z1.y));
            vn1.z = a1.z + (ELOG - EPS * __logf(z1.z));
            vn1.w = a1.w + (ELOG - EPS * __logf(z1.w));
            if ((blockIdx.x & (PCHUNKS - 1)) == 0) {         // 1 writer/batch
                float4* vw4 = (float4*)(vw + n * P2);
                vw4[t] = vn0; vw4[t + 256] = vn1;
            }
        }
        float4 b0, b1;
        b0.x = vn0.x * INV_EPS; b0.y = vn0.y * INV_EPS;
        b0.z = vn0.z * INV_EPS; b0.w = vn0.w * INV_EPS;
        b1.x = vn1.x * INV_EPS; b1.y = vn1.y * INV_EPS;
        b1.z = vn1.z * INV_EPS; b1.w = vn1.w * INV_EPS;
        ((float4*)bl)[t] = b0;
        ((float4*)bl)[t + 256] = b1;
    }
    __syncthreads();

    int wave = t >> 6, lane = t & 63;
    int irow = i0 + wave * 4;
    float* arow = u + n * P1 + irow;
    float a0 = arow[0], a1 = arow[1], a2 = arow[2], a3 = arow[3];
    const float4* base = (const float4*)(C + ((size_t)(n * P1 + irow)) * P2);

    float4 S[8];
    #pragma unroll
    for (int k = 0; k < 8; ++k) S[k] = make_float4(0.0f, 0.0f, 0.0f, 0.0f);

    float4 X[8], Y[8], Zr[8];
    load_row8(X, base, lane);            // row 0
    load_row8(Y, base + RP, lane);       // row 1 in flight
    load_row8(Zr, base + 2 * RP, lane);  // row 2 in flight
    float s0 = row_sum(X, a0 * INV_EPS, bl, lane);
    float d0 = ELOG - EPS * __logf(s0);
    acc_row(S, X, __fdividef(MU_VAL, s0));
    load_row8(X, base + 3 * RP, lane);   // row 3 in flight
    float s1 = row_sum(Y, a1 * INV_EPS, bl, lane);
    float d1 = ELOG - EPS * __logf(s1);
    acc_row(S, Y, __fdividef(MU_VAL, s1));
    float s2 = row_sum(Zr, a2 * INV_EPS, bl, lane);
    float d2 = ELOG - EPS * __logf(s2);
    acc_row(S, Zr, __fdividef(MU_VAL, s2));
    float s3 = row_sum(X, a3 * INV_EPS, bl, lane);
    float d3 = ELOG - EPS * __logf(s3);
    acc_row(S, X, __fdividef(MU_VAL, s3));

    if (lane == 0) {
        arow[0] = a0 + d0; arow[1] = a1 + d1;
        arow[2] = a2 + d2; arow[3] = a3 + d3;
        da_s[wave] = fabsf(d0) + fabsf(d1) + fabsf(d2) + fabsf(d3);
    }

    // cross-wave column sum through LDS, then atomics into Z[t]
    #pragma unroll
    for (int k = 0; k < 8; ++k) LS[wave][lane + 64 * k] = S[k];
    __syncthreads();

    float* zt = Zb + ((size_t)t_iter * NB + n) * P2;
    #pragma unroll
    for (int sl = 0; sl < 2; ++sl) {
        int slot = t + 256 * sl;
        float4 x0 = LS[0][slot], x1 = LS[1][slot];
        float4 x2 = LS[2][slot], x3 = LS[3][slot];
        float4 o;
        o.x = (x0.x + x1.x) + (x2.x + x3.x);
        o.y = (x0.y + x1.y) + (x2.y + x3.y);
        o.z = (x0.z + x1.z) + (x2.z + x3.z);
        o.w = (x0.w + x1.w) + (x2.w + x3.w);
        int j = 4 * slot;
        atomicAdd(&zt[j + 0], o.x);
        atomicAdd(&zt[j + 1], o.y);
        atomicAdd(&zt[j + 2], o.z);
        atomicAdd(&zt[j + 3], o.w);
    }

    if (t == 0) {
        atomicAdd(&errAcc[t_iter * ERRSLOTS + (blockIdx.x & (ERRSLOTS - 1))],
                  da_s[0] + da_s[1] + da_s[2] + da_s[3]);
    }
}

// ---------------------------------------------------------------------------
// v_fin: materialize final v into the v array (one launch, after the loop).
// Last active iteration k: v_final = buf[(k-1)&1] + ELOG - eps*log(Z[k]).
// k==0 (frozen after t=0): v_comb already wrote final v — nothing to do.
// ---------------------------------------------------------------------------
__global__ void v_fin(float* __restrict__ v, const float* __restrict__ v2,
                      const float* __restrict__ Zb, const int* __restrict__ active) {
    int k = 0;
    for (int q = 1; q < ITER; ++q) if (active[q]) k = q;
    if (k == 0) return;
    int n = blockIdx.x >> 3;                         // 32 blocks, 8/batch
    int j = ((blockIdx.x & 7) << 8) + threadIdx.x;   // 0..2047
    const float* vb = ((k - 1) & 1) ? v2 : v;
    float zv = Zb[((size_t)k * NB + n) * P2 + j];
    v[n * P2 + j] = vb[n * P2 + j] + ELOG - EPS * __logf(zv);
}

// ---------------------------------------------------------------------------
// final_pass: pi = exp((u_i - C + v_j)/eps), cost_n = sum(pi*C).
// Pipelined 16-rows/block structure (r1/r4 validated).
// ---------------------------------------------------------------------------
__device__ __forceinline__ float row_pi(const float4 c[8], float ui, const float* vl,
                                        int lane, float4* prow) {
    float acc = 0.0f;
    #pragma unroll
    for (int k = 0; k < 8; ++k) {
        float4 vv = ((const float4*)vl)[lane + 64 * k];
        float4 p;
        p.x = __expf(((ui - c[k].x) + vv.x) * INV_EPS);
        p.y = __expf(((ui - c[k].y) + vv.y) * INV_EPS);
        p.z = __expf(((ui - c[k].z) + vv.z) * INV_EPS);
        p.w = __expf(((ui - c[k].w) + vv.w) * INV_EPS);
        prow[lane + 64 * k] = p;
        acc += p.x * c[k].x + p.y * c[k].y + p.z * c[k].z + p.w * c[k].w;
    }
    return acc;
}

__global__ __launch_bounds__(256) void final_pass(const float* __restrict__ C,
                                                  const float* __restrict__ u,
                                                  const float* __restrict__ v,
                                                  float* __restrict__ pi,
                                                  float* __restrict__ cost) {
    __shared__ float vl[P2];
    __shared__ float red[4];
    int t = threadIdx.x;
    int n = blockIdx.x >> 7;
    int i0 = (blockIdx.x & 127) * 16;
    {
        const float4* vsrc = (const float4*)(v + n * P2);
        ((float4*)vl)[t] = vsrc[t];
        ((float4*)vl)[t + 256] = vsrc[t + 256];
    }
    __syncthreads();

    int wave = t >> 6, lane = t & 63;
    int irow = i0 + wave * 4;
    const float* urow = u + n * P1 + irow;
    float u0 = urow[0], u1 = urow[1], u2 = urow[2], u3 = urow[3];
    const float4* base = (const float4*)(C + ((size_t)(n * P1 + irow)) * P2);
    float4* pbase = (float4*)(pi + ((size_t)(n * P1 + irow)) * P2);

    float4 A[8], B[8];
    load_row8(A, base, lane);
    load_row8(B, base + RP, lane);
    float acc = row_pi(A, u0, vl, lane, pbase);
    load_row8(A, base + 2 * RP, lane);
    acc += row_pi(B, u1, vl, lane, pbase + RP);
    load_row8(B, base + 3 * RP, lane);
    acc += row_pi(A, u2, vl, lane, pbase + 2 * RP);
    acc += row_pi(B, u3, vl, lane, pbase + 3 * RP);

    #pragma unroll
    for (int o = 1; o < 64; o <<= 1) acc += __shfl_xor(acc, o, 64);
    if (lane == 0) red[wave] = acc;
    __syncthreads();
    if (t == 0) atomicAdd(&cost[n], red[0] + red[1] + red[2] + red[3]);
}

// ---------------------------------------------------------------------------
extern "C" void kernel_launch(void* const* d_in, const int* in_sizes, int n_in,
                              void* d_out, int out_size, void* d_ws, size_t ws_size,
                              hipStream_t stream) {
    const float* x = (const float*)d_in[0];   // [N,P1,D]
    const float* y = (const float*)d_in[1];   // [N,P2,D]
    const float* M = (const float*)d_in[2];   // [D,D]
    float* out = (float*)d_out;
    float* cost = out;                                    // [N]
    float* pi = out + NB;                                 // [N,P1,P2]
    float* C = out + NB + (size_t)NB * P1 * P2;           // [N,P1,P2]

    float* ws = (float*)d_ws;
    float* S      = ws;                                   // 4096
    float* xS     = S + DD * DD;                          // N*P1*D
    float* dx     = xS + (size_t)NB * P1 * DD;            // N*P1
    float* dy     = dx + NB * P1;                         // N*P2
    float* u      = dy + NB * P2;                         // N*P1
    float* v      = u + NB * P1;                          // N*P2   (buf0)
    float* errAcc = v + NB * P2;                          // ITER*ERRSLOTS
    int*   active = (int*)(errAcc + ITER * ERRSLOTS);     // 64 ints
    float* v2     = (float*)(active + 64);                // N*P2   (buf1)

    // Scratch in the dead pi region (pi is only written by final_pass, and
    // every reader of these buffers runs before final_pass — stream order):
    //   Z  : [ITER][NB][P2]  atomic column sums   (1.6 MB)
    //   pm : [NB][PCHUNKS][P2]  t=0 maxima        (4.2 MB)
    //   ps : [NB][PCHUNKS][P2]  t=0 sums          (4.2 MB)
    float* Zb = pi;
    float* pm = Zb + (size_t)ITER * NB * P2;
    float* ps = pm + (size_t)NB * PCHUNKS * P2;

    prep0<<<128, 256, 0, stream>>>(M, S, errAcc, active, cost, Zb);
    prep1<<<(NB * (P1 + P2)) / 4, 256, 0, stream>>>(x, y, S, xS, dx, dy, u, v);
    gemmC<<<dim3(P2 / 64, P1 / 64, NB), 256, 0, stream>>>(xS, y, dx, dy, C);
    // t = 0: unbounded q = -C -> max-safe slow path (writes v = buf0).
    iter_pass<<<NB * PCHUNKS, 256, 0, stream>>>(C, u, v, pm, ps, errAcc, active, 0);
    v_comb<<<NB * 32, 256, 0, stream>>>(pm, ps, v, errAcc, active, 0);
    // t >= 1: fused fast path — one kernel per iteration.
    for (int t = 1; t < ITER; ++t) {
        iter_fused<<<NB * PCHUNKS, 256, 0, stream>>>(C, u, v, v2, Zb, errAcc,
                                                     active, t);
    }
    v_fin<<<32, 256, 0, stream>>>(v, v2, Zb, active);
    final_pass<<<NB * P1 / 16, 256, 0, stream>>>(C, u, v, pi, cost);
}

// Round 7
// 1044.724 us; speedup vs baseline: 2.0061x; 2.0061x over previous
//
#include <hip/hip_runtime.h>
#include <cstdint>
#include <cstddef>

// Problem constants (reference: N=4, P1=P2=2048, D=64, eps=0.1, 50 iters)
#define NB 4
#define P1 2048
#define P2 2048
#define DD 64
#define ITER 50
#define EPS 0.1f
#define INV_EPS 10.0f          // 1.0f/0.1f rounds to exactly 10.0f
#define THRESH 0.1f
// log(1/2048 + 1e-8) in fp32
#define LOG_MU -7.6245985f
#define ELOG (-0.76245985f)    // EPS * LOG_MU (== EPS * LOG_NU)
#define MU_VAL 0.00048829125f  // exp(LOG_MU) = 1/2048 + 1e-8
#define ERRSLOTS 32
#define RP (P2 / 4)            // float4s per row
#define PCHUNKS 128            // iter blocks per batch (16 rows each)

// ---------------------------------------------------------------------------
// prep0: S = M + M^T, zero err accumulators, init active flags, zero cost out
// ---------------------------------------------------------------------------
__global__ void prep0(const float* __restrict__ M, float* __restrict__ S,
                      float* __restrict__ errAcc, int* __restrict__ active,
                      float* __restrict__ cost) {
    int t = threadIdx.x;
    for (int k = t; k < DD * DD; k += 256) {
        int d = k >> 6, e = k & 63;
        S[k] = M[d * DD + e] + M[e * DD + d];
    }
    for (int k = t; k < ITER * ERRSLOTS; k += 256) errAcc[k] = 0.0f;
    if (t < 64) active[t] = (t == 0) ? 1 : 0;
    if (t < NB) cost[t] = 0.0f;
}

// ---------------------------------------------------------------------------
// prep1: one wave per row. x-rows: xS = x@S, dx = 0.5*x·(Sx), u=0.
//        y-rows: dy = 0.5*y·(Sy), v=0.
// ---------------------------------------------------------------------------
__global__ __launch_bounds__(256) void prep1(const float* __restrict__ x,
                                             const float* __restrict__ y,
                                             const float* __restrict__ S,
                                             float* __restrict__ xS,
                                             float* __restrict__ dx,
                                             float* __restrict__ dy,
                                             float* __restrict__ u,
                                             float* __restrict__ v) {
    __shared__ float Sl[DD * DD];
    int t = threadIdx.x;
    for (int k = t; k < DD * DD; k += 256) Sl[k] = S[k];
    __syncthreads();
    int wave = t >> 6, lane = t & 63;
    int r = blockIdx.x * 4 + wave;          // 0 .. N*(P1+P2)-1
    bool isX = r < NB * P1;
    const float* src = isX ? x : y;
    int rr = isX ? r : r - NB * P1;
    float xv = src[(size_t)rr * DD + lane];
    float acc = 0.0f;
    #pragma unroll
    for (int d = 0; d < DD; ++d) {
        float xd = __shfl(xv, d, 64);
        acc = fmaf(xd, Sl[d * DD + lane], acc);
    }
    float p = acc * xv;
    #pragma unroll
    for (int o = 32; o; o >>= 1) p += __shfl_xor(p, o, 64);
    if (isX) {
        xS[(size_t)rr * DD + lane] = acc;
        if (lane == 0) { dx[rr] = 0.5f * p; u[rr] = 0.0f; }
    } else {
        if (lane == 0) { dy[rr] = 0.5f * p; v[rr] = 0.0f; }
    }
}

// ---------------------------------------------------------------------------
// gemmC: C[n,i,j] = dx[n,i] + dy[n,j] - sum_e xS[n,i,e]*y[n,j,e]
// 64x64 tile per 256-thread block, 4x4 register tile per thread.
// ---------------------------------------------------------------------------
__global__ __launch_bounds__(256) void gemmC(const float* __restrict__ xS,
                                             const float* __restrict__ y,
                                             const float* __restrict__ dx,
                                             const float* __restrict__ dy,
                                             float* __restrict__ C) {
    __shared__ float xs[64][68];
    __shared__ float ys[64][68];
    int n = blockIdx.z;
    int i0 = blockIdx.y * 64, j0 = blockIdx.x * 64;
    int t = threadIdx.x;

    #pragma unroll
    for (int k = 0; k < 4; ++k) {
        int f = t + 256 * k;       // 0..1023
        int row = f >> 4;          // 0..63
        int c4 = f & 15;           // 0..15
        float4 a = ((const float4*)xS)[((size_t)(n * P1 + i0 + row)) * (DD / 4) + c4];
        xs[4 * c4 + 0][row] = a.x; xs[4 * c4 + 1][row] = a.y;
        xs[4 * c4 + 2][row] = a.z; xs[4 * c4 + 3][row] = a.w;
        float4 b = ((const float4*)y)[((size_t)(n * P2 + j0 + row)) * (DD / 4) + c4];
        ys[4 * c4 + 0][row] = b.x; ys[4 * c4 + 1][row] = b.y;
        ys[4 * c4 + 2][row] = b.z; ys[4 * c4 + 3][row] = b.w;
    }
    __syncthreads();

    int tx = t & 15, ty = t >> 4;
    float acc[4][4] = {};
    #pragma unroll
    for (int e = 0; e < 64; ++e) {
        float4 a = *(const float4*)&xs[e][4 * ty];
        float4 b = *(const float4*)&ys[e][4 * tx];
        acc[0][0] = fmaf(a.x, b.x, acc[0][0]); acc[0][1] = fmaf(a.x, b.y, acc[0][1]);
        acc[0][2] = fmaf(a.x, b.z, acc[0][2]); acc[0][3] = fmaf(a.x, b.w, acc[0][3]);
        acc[1][0] = fmaf(a.y, b.x, acc[1][0]); acc[1][1] = fmaf(a.y, b.y, acc[1][1]);
        acc[1][2] = fmaf(a.y, b.z, acc[1][2]); acc[1][3] = fmaf(a.y, b.w, acc[1][3]);
        acc[2][0] = fmaf(a.z, b.x, acc[2][0]); acc[2][1] = fmaf(a.z, b.y, acc[2][1]);
        acc[2][2] = fmaf(a.z, b.z, acc[2][2]); acc[2][3] = fmaf(a.z, b.w, acc[2][3]);
        acc[3][0] = fmaf(a.w, b.x, acc[3][0]); acc[3][1] = fmaf(a.w, b.y, acc[3][1]);
        acc[3][2] = fmaf(a.w, b.z, acc[3][2]); acc[3][3] = fmaf(a.w, b.w, acc[3][3]);
    }

    int iBase = i0 + ty * 4, jBase = j0 + tx * 4;
    float4 dy4 = *(const float4*)&dy[n * P2 + jBase];
    #pragma unroll
    for (int r = 0; r < 4; ++r) {
        float dxv = dx[n * P1 + iBase + r];
        float4 o;
        o.x = dxv + dy4.x - acc[r][0];
        o.y = dxv + dy4.y - acc[r][1];
        o.z = dxv + dy4.z - acc[r][2];
        o.w = dxv + dy4.w - acc[r][3];
        *(float4*)&C[((size_t)(n * P1 + iBase + r)) * P2 + jBase] = o;
    }
}

// ---------------------------------------------------------------------------
// Row helpers (r4-validated)
// ---------------------------------------------------------------------------
__device__ __forceinline__ void load_row8(float4 dst[8], const float4* base, int lane) {
    #pragma unroll
    for (int k = 0; k < 8; ++k) dst[k] = base[lane + 64 * k];
}

// Transforms c in place to q = (ai - C) + b; returns eps*LSE_j(q_j/eps).
__device__ __forceinline__ float row_lse(float4 c[8], float ai, const float* bl, int lane) {
    float m = -3.4e38f;
    #pragma unroll
    for (int k = 0; k < 8; ++k) {
        float4 vv = ((const float4*)bl)[lane + 64 * k];
        c[k].x = (ai - c[k].x) + vv.x;
        c[k].y = (ai - c[k].y) + vv.y;
        c[k].z = (ai - c[k].z) + vv.z;
        c[k].w = (ai - c[k].w) + vv.w;
        m = fmaxf(m, fmaxf(fmaxf(c[k].x, c[k].y), fmaxf(c[k].z, c[k].w)));
    }
    #pragma unroll
    for (int o = 1; o < 64; o <<= 1) m = fmaxf(m, __shfl_xor(m, o, 64));
    float s = 0.0f;
    #pragma unroll
    for (int k = 0; k < 8; ++k)
        s += __expf((c[k].x - m) * INV_EPS) + __expf((c[k].y - m) * INV_EPS) +
             __expf((c[k].z - m) * INV_EPS) + __expf((c[k].w - m) * INV_EPS);
    #pragma unroll
    for (int o = 1; o < 64; o <<= 1) s += __shfl_xor(s, o, 64);
    return EPS * __logf(s) + m;
}

// Online (m,s) merge of one scalar term q (values in C-units, exp scaled by 1/eps)
__device__ __forceinline__ void mergec(float& m, float& s, float q) {
    float nm = fmaxf(m, q);
    s = s * __expf((m - nm) * INV_EPS) + __expf((q - nm) * INV_EPS);
    m = nm;
}
__device__ __forceinline__ void mergems(float& m, float& s, float mo, float so) {
    float nm = fmaxf(m, mo);
    s = s * __expf((m - nm) * INV_EPS) + so * __expf((mo - nm) * INV_EPS);
    m = nm;
}
__device__ __forceinline__ void merge44(float4& m, float4& s, float4 mo, float4 so) {
    mergems(m.x, s.x, mo.x, so.x);
    mergems(m.y, s.y, mo.y, so.y);
    mergems(m.z, s.z, mo.z, so.z);
    mergems(m.w, s.w, mo.w, so.w);
}

// Merge row's q (+wave-uniform dr = u_new - u_old) into per-column (M,S) regs.
__device__ __forceinline__ void merge_row(float4 M[8], float4 S[8],
                                          const float4 q[8], float dr) {
    #pragma unroll
    for (int k = 0; k < 8; ++k) {
        mergec(M[k].x, S[k].x, q[k].x + dr);
        mergec(M[k].y, S[k].y, q[k].y + dr);
        mergec(M[k].z, S[k].z, q[k].z + dr);
        mergec(M[k].w, S[k].w, q[k].w + dr);
    }
}

// ---------------------------------------------------------------------------
// iter_pass (max-safe, t=0 only — q=-C unbounded): full Sinkhorn u-update
// plus in-register per-column (m,s) partials. 16 rows/block, 512 blocks.
// ---------------------------------------------------------------------------
__global__ __launch_bounds__(256) void iter_pass(const float* __restrict__ C,
                                                 float* __restrict__ u,
                                                 const float* __restrict__ v,
                                                 float* __restrict__ pm,
                                                 float* __restrict__ ps,
                                                 float* __restrict__ errAcc,
                                                 const int* __restrict__ active,
                                                 int t_iter) {
    if (!active[t_iter]) return;
    __shared__ float bl[P2];          // 8 KB: v values for this batch
    __shared__ float4 LM[4][512];     // 32 KB: per-wave column maxima
    __shared__ float4 LS[4][512];     // 32 KB: per-wave column sums
    __shared__ float da_s[4];
    int t = threadIdx.x;
    int n = blockIdx.x >> 7;                       // PCHUNKS=128 blocks/batch
    int i0 = (blockIdx.x & (PCHUNKS - 1)) * 16;
    {
        const float4* bsrc = (const float4*)(v + n * P2);
        ((float4*)bl)[t] = bsrc[t];
        ((float4*)bl)[t + 256] = bsrc[t + 256];
    }
    __syncthreads();

    int wave = t >> 6, lane = t & 63;
    int irow = i0 + wave * 4;
    float* arow = u + n * P1 + irow;
    float a0 = arow[0], a1 = arow[1], a2 = arow[2], a3 = arow[3];
    const float4* base = (const float4*)(C + ((size_t)(n * P1 + irow)) * P2);

    float4 M[8], S[8];
    #pragma unroll
    for (int k = 0; k < 8; ++k) {
        M[k] = make_float4(-3.4e38f, -3.4e38f, -3.4e38f, -3.4e38f);
        S[k] = make_float4(0.0f, 0.0f, 0.0f, 0.0f);
    }

    float4 A[8], B[8];
    load_row8(A, base, lane);
    load_row8(B, base + RP, lane);
    float l0 = row_lse(A, a0, bl, lane);
    float d0 = ELOG - l0;
    merge_row(M, S, A, d0);
    load_row8(A, base + 2 * RP, lane);
    float l1 = row_lse(B, a1, bl, lane);
    float d1 = ELOG - l1;
    merge_row(M, S, B, d1);
    load_row8(B, base + 3 * RP, lane);
    float l2 = row_lse(A, a2, bl, lane);
    float d2 = ELOG - l2;
    merge_row(M, S, A, d2);
    float l3 = row_lse(B, a3, bl, lane);
    float d3 = ELOG - l3;
    merge_row(M, S, B, d3);

    if (lane == 0) {
        arow[0] = a0 + d0; arow[1] = a1 + d1;
        arow[2] = a2 + d2; arow[3] = a3 + d3;
        da_s[wave] = fabsf(d0) + fabsf(d1) + fabsf(d2) + fabsf(d3);
    }

    // cross-wave column merge through LDS
    #pragma unroll
    for (int k = 0; k < 8; ++k) {
        LM[wave][lane + 64 * k] = M[k];
        LS[wave][lane + 64 * k] = S[k];
    }
    __syncthreads();

    float4* pm4 = (float4*)pm;
    float4* ps4 = (float4*)ps;
    size_t pb4 = (size_t)blockIdx.x * 512;
    #pragma unroll
    for (int sl = 0; sl < 2; ++sl) {
        int slot = t + 256 * sl;
        float4 m = LM[0][slot], s = LS[0][slot];
        merge44(m, s, LM[1][slot], LS[1][slot]);
        merge44(m, s, LM[2][slot], LS[2][slot]);
        merge44(m, s, LM[3][slot], LS[3][slot]);
        pm4[pb4 + slot] = m;
        ps4[pb4 + slot] = s;
    }

    if (t == 0) {
        atomicAdd(&errAcc[t_iter * ERRSLOTS + (blockIdx.x & (ERRSLOTS - 1))],
                  da_s[0] + da_s[1] + da_s[2] + da_s[3]);
    }
}

// ---------------------------------------------------------------------------
// v_comb (t=0 only): merge PCHUNKS (m,s) partials per column, apply v update,
// advance active.
// ---------------------------------------------------------------------------
__global__ __launch_bounds__(256) void v_comb(const float* __restrict__ pm,
                                              const float* __restrict__ ps,
                                              float* __restrict__ v,
                                              const float* __restrict__ errAcc,
                                              int* __restrict__ active,
                                              int t_iter) {
    if (blockIdx.x == 0 && threadIdx.x == 0) {
        float e = 0.0f;
        #pragma unroll
        for (int q = 0; q < ERRSLOTS; ++q) e += errAcc[t_iter * ERRSLOTS + q];
        if (active[t_iter] && (e * 0.25f >= THRESH)) active[t_iter + 1] = 1;
    }
    if (!active[t_iter]) return;
    __shared__ float LMv[4][64];
    __shared__ float LSv[4][64];
    int t = threadIdx.x, wave = t >> 6, lane = t & 63;
    int n = blockIdx.x >> 5;
    int j = ((blockIdx.x & 31) << 6) + lane;
    const float* pmb = pm + ((size_t)(n * PCHUNKS + wave * 32)) * P2 + j;
    const float* psb = ps + ((size_t)(n * PCHUNKS + wave * 32)) * P2 + j;
    float m0 = -3.4e38f, s0 = 0.0f, m1 = -3.4e38f, s1 = 0.0f;
    float m2 = -3.4e38f, s2 = 0.0f, m3 = -3.4e38f, s3 = 0.0f;
    #pragma unroll
    for (int c = 0; c < 32; c += 4) {
        mergems(m0, s0, pmb[(size_t)(c + 0) * P2], psb[(size_t)(c + 0) * P2]);
        mergems(m1, s1, pmb[(size_t)(c + 1) * P2], psb[(size_t)(c + 1) * P2]);
        mergems(m2, s2, pmb[(size_t)(c + 2) * P2], psb[(size_t)(c + 2) * P2]);
        mergems(m3, s3, pmb[(size_t)(c + 3) * P2], psb[(size_t)(c + 3) * P2]);
    }
    mergems(m0, s0, m1, s1);
    mergems(m2, s2, m3, s3);
    mergems(m0, s0, m2, s2);
    LMv[wave][lane] = m0; LSv[wave][lane] = s0;
    __syncthreads();
    if (wave == 0) {
        float m = LMv[0][lane], s = LSv[0][lane];
        mergems(m, s, LMv[1][lane], LSv[1][lane]);
        mergems(m, s, LMv[2][lane], LSv[2][lane]);
        mergems(m, s, LMv[3][lane], LSv[3][lane]);
        float lse = EPS * __logf(s) + m;
        v[n * P2 + j] = v[n * P2 + j] + ELOG - lse;
    }
}

// ---------------------------------------------------------------------------
// FAST PATH (t >= 1). Invariant (r5-validated): after iteration 0's full
// (u,v) update, every exp((u-C+v)/eps) <= MU and row/col sums live in
// [2.4e-7, 4.4e6] -> plain fp32 sums, no max tracking. u,v stay in the
// LOG domain (the r2 multiplicative-tilt path accumulated drift and NaN'd).
// ---------------------------------------------------------------------------
__device__ __forceinline__ float row_sum(float4 c[8], float aiv, const float* bl,
                                         int lane) {
    float s = 0.0f;
    #pragma unroll
    for (int k = 0; k < 8; ++k) {
        float4 vv = ((const float4*)bl)[lane + 64 * k];
        c[k].x = __expf(fmaf(c[k].x, -INV_EPS, aiv + vv.x));
        c[k].y = __expf(fmaf(c[k].y, -INV_EPS, aiv + vv.y));
        c[k].z = __expf(fmaf(c[k].z, -INV_EPS, aiv + vv.z));
        c[k].w = __expf(fmaf(c[k].w, -INV_EPS, aiv + vv.w));
        s += (c[k].x + c[k].y) + (c[k].z + c[k].w);
    }
    #pragma unroll
    for (int o = 1; o < 64; o <<= 1) s += __shfl_xor(s, o, 64);
    return s;
}

__device__ __forceinline__ void acc_row(float4 S[8], const float4 q[8], float ed) {
    #pragma unroll
    for (int k = 0; k < 8; ++k) {
        S[k].x = fmaf(q[k].x, ed, S[k].x);
        S[k].y = fmaf(q[k].y, ed, S[k].y);
        S[k].z = fmaf(q[k].z, ed, S[k].z);
        S[k].w = fmaf(q[k].w, ed, S[k].w);
    }
}

// iter_fast: 16 rows/block, 512 blocks — SAME block count / grid / partial
// layout as the validated r4 kernel (all structures that changed block count
// or used atomic epilogues regressed 2x: r3/r5/r6). ONE change vs r4:
// 512 threads = 8 waves/block, 2 rows/wave (was 4 waves x 4 rows).
// LDS = 8KB v-tile + 64KB LS + da_s ~= 72KB -> still 2 blocks/CU, but
// 16 waves/CU instead of 8 (4 waves/SIMD). Per-wave live arrays shrink to
// X[8]+Y[8]+S[8] = 96 VGPRs (+temps ~= 120), under the 128-VGPR 4-wave
// budget; no launch-bounds cap so worst case is 3 waves/SIMD, never spill.
// Theory: kernel is latency-bound at 8 waves/CU (4 TB/s eff. BW, low VALU);
// doubling resident waves doubles latency hiding at constant per-block cost.
__global__ __launch_bounds__(512) void iter_fast(const float* __restrict__ C,
                                                 float* __restrict__ u,
                                                 const float* __restrict__ v,
                                                 float* __restrict__ ps,
                                                 float* __restrict__ errAcc,
                                                 const int* __restrict__ active,
                                                 int t_iter) {
    if (!active[t_iter]) return;
    __shared__ float bl[P2];          // 8 KB: v*INV_EPS for this batch
    __shared__ float4 LS[8][512];     // 64 KB: per-wave column sums
    __shared__ float da_s[8];
    int t = threadIdx.x;              // 0..511
    int n = blockIdx.x >> 7;
    int i0 = (blockIdx.x & (PCHUNKS - 1)) * 16;
    {
        const float4* bsrc = (const float4*)(v + n * P2);
        float4 b0 = bsrc[t];
        b0.x *= INV_EPS; b0.y *= INV_EPS; b0.z *= INV_EPS; b0.w *= INV_EPS;
        ((float4*)bl)[t] = b0;
    }
    __syncthreads();

    int wave = t >> 6, lane = t & 63;
    int irow = i0 + wave * 2;
    float* arow = u + n * P1 + irow;
    float a0 = arow[0], a1 = arow[1];
    const float4* base = (const float4*)(C + ((size_t)(n * P1 + irow)) * P2);

    float4 S[8];
    #pragma unroll
    for (int k = 0; k < 8; ++k) S[k] = make_float4(0.0f, 0.0f, 0.0f, 0.0f);

    float4 X[8], Y[8];
    load_row8(X, base, lane);          // row 0
    load_row8(Y, base + RP, lane);     // row 1 in flight during row 0 compute
    float s0 = row_sum(X, a0 * INV_EPS, bl, lane);
    float d0 = ELOG - EPS * __logf(s0);
    acc_row(S, X, __fdividef(MU_VAL, s0));
    float s1 = row_sum(Y, a1 * INV_EPS, bl, lane);
    float d1 = ELOG - EPS * __logf(s1);
    acc_row(S, Y, __fdividef(MU_VAL, s1));

    if (lane == 0) {
        arow[0] = a0 + d0; arow[1] = a1 + d1;
        da_s[wave] = fabsf(d0) + fabsf(d1);
    }

    // cross-wave column sum through LDS (plain adds)
    #pragma unroll
    for (int k = 0; k < 8; ++k) LS[wave][lane + 64 * k] = S[k];
    __syncthreads();

    float4* ps4 = (float4*)ps;
    size_t pb4 = (size_t)blockIdx.x * 512;
    {
        int slot = t;                  // 512 threads cover all 512 slots
        float4 x0 = LS[0][slot], x1 = LS[1][slot];
        float4 x2 = LS[2][slot], x3 = LS[3][slot];
        float4 x4 = LS[4][slot], x5 = LS[5][slot];
        float4 x6 = LS[6][slot], x7 = LS[7][slot];
        float4 o;
        o.x = ((x0.x + x1.x) + (x2.x + x3.x)) + ((x4.x + x5.x) + (x6.x + x7.x));
        o.y = ((x0.y + x1.y) + (x2.y + x3.y)) + ((x4.y + x5.y) + (x6.y + x7.y));
        o.z = ((x0.z + x1.z) + (x2.z + x3.z)) + ((x4.z + x5.z) + (x6.z + x7.z));
        o.w = ((x0.w + x1.w) + (x2.w + x3.w)) + ((x4.w + x5.w) + (x6.w + x7.w));
        ps4[pb4 + slot] = o;
    }

    if (t == 0) {
        atomicAdd(&errAcc[t_iter * ERRSLOTS + (blockIdx.x & (ERRSLOTS - 1))],
                  ((da_s[0] + da_s[1]) + (da_s[2] + da_s[3])) +
                  ((da_s[4] + da_s[5]) + (da_s[6] + da_s[7])));
    }
}

// v_fast: plain-sum merge of PCHUNKS=128 partials per column, v update,
// advance active. 128 blocks; wave w merges chunks [32w, 32w+32).
__global__ __launch_bounds__(256) void v_fast(const float* __restrict__ ps,
                                              float* __restrict__ v,
                                              const float* __restrict__ errAcc,
                                              int* __restrict__ active,
                                              int t_iter) {
    if (blockIdx.x == 0 && threadIdx.x == 0) {
        float e = 0.0f;
        #pragma unroll
        for (int q = 0; q < ERRSLOTS; ++q) e += errAcc[t_iter * ERRSLOTS + q];
        if (active[t_iter] && (e * 0.25f >= THRESH)) active[t_iter + 1] = 1;
    }
    if (!active[t_iter]) return;
    __shared__ float LSv[4][64];
    int t = threadIdx.x, wave = t >> 6, lane = t & 63;
    int n = blockIdx.x >> 5;
    int j = ((blockIdx.x & 31) << 6) + lane;
    const float* psb = ps + ((size_t)(n * PCHUNKS + wave * 32)) * P2 + j;
    float s0 = 0.0f, s1 = 0.0f, s2 = 0.0f, s3 = 0.0f;
    #pragma unroll
    for (int c = 0; c < 32; c += 4) {
        s0 += psb[(size_t)(c + 0) * P2];
        s1 += psb[(size_t)(c + 1) * P2];
        s2 += psb[(size_t)(c + 2) * P2];
        s3 += psb[(size_t)(c + 3) * P2];
    }
    LSv[wave][lane] = (s0 + s1) + (s2 + s3);
    __syncthreads();
    if (wave == 0) {
        float s = (LSv[0][lane] + LSv[1][lane]) + (LSv[2][lane] + LSv[3][lane]);
        v[n * P2 + j] = v[n * P2 + j] + ELOG - EPS * __logf(s);
    }
}

// ---------------------------------------------------------------------------
// final_pass: pi = exp((u_i - C + v_j)/eps), cost_n = sum(pi*C).
// Pipelined 16-rows/block structure (round-1/4 validated).
// ---------------------------------------------------------------------------
__device__ __forceinline__ float row_pi(const float4 c[8], float ui, const float* vl,
                                        int lane, float4* prow) {
    float acc = 0.0f;
    #pragma unroll
    for (int k = 0; k < 8; ++k) {
        float4 vv = ((const float4*)vl)[lane + 64 * k];
        float4 p;
        p.x = __expf(((ui - c[k].x) + vv.x) * INV_EPS);
        p.y = __expf(((ui - c[k].y) + vv.y) * INV_EPS);
        p.z = __expf(((ui - c[k].z) + vv.z) * INV_EPS);
        p.w = __expf(((ui - c[k].w) + vv.w) * INV_EPS);
        prow[lane + 64 * k] = p;
        acc += p.x * c[k].x + p.y * c[k].y + p.z * c[k].z + p.w * c[k].w;
    }
    return acc;
}

__global__ __launch_bounds__(256) void final_pass(const float* __restrict__ C,
                                                  const float* __restrict__ u,
                                                  const float* __restrict__ v,
                                                  float* __restrict__ pi,
                                                  float* __restrict__ cost) {
    __shared__ float vl[P2];
    __shared__ float red[4];
    int t = threadIdx.x;
    int n = blockIdx.x >> 7;
    int i0 = (blockIdx.x & 127) * 16;
    {
        const float4* vsrc = (const float4*)(v + n * P2);
        ((float4*)vl)[t] = vsrc[t];
        ((float4*)vl)[t + 256] = vsrc[t + 256];
    }
    __syncthreads();

    int wave = t >> 6, lane = t & 63;
    int irow = i0 + wave * 4;
    const float* urow = u + n * P1 + irow;
    float u0 = urow[0], u1 = urow[1], u2 = urow[2], u3 = urow[3];
    const float4* base = (const float4*)(C + ((size_t)(n * P1 + irow)) * P2);
    float4* pbase = (float4*)(pi + ((size_t)(n * P1 + irow)) * P2);

    float4 A[8], B[8];
    load_row8(A, base, lane);
    load_row8(B, base + RP, lane);
    float acc = row_pi(A, u0, vl, lane, pbase);
    load_row8(A, base + 2 * RP, lane);
    acc += row_pi(B, u1, vl, lane, pbase + RP);
    load_row8(B, base + 3 * RP, lane);
    acc += row_pi(A, u2, vl, lane, pbase + 2 * RP);
    acc += row_pi(B, u3, vl, lane, pbase + 3 * RP);

    #pragma unroll
    for (int o = 1; o < 64; o <<= 1) acc += __shfl_xor(acc, o, 64);
    if (lane == 0) red[wave] = acc;
    __syncthreads();
    if (t == 0) atomicAdd(&cost[n], red[0] + red[1] + red[2] + red[3]);
}

// ---------------------------------------------------------------------------
extern "C" void kernel_launch(void* const* d_in, const int* in_sizes, int n_in,
                              void* d_out, int out_size, void* d_ws, size_t ws_size,
                              hipStream_t stream) {
    const float* x = (const float*)d_in[0];   // [N,P1,D]
    const float* y = (const float*)d_in[1];   // [N,P2,D]
    const float* M = (const float*)d_in[2];   // [D,D]
    float* out = (float*)d_out;
    float* cost = out;                                    // [N]
    float* pi = out + NB;                                 // [N,P1,P2]
    float* C = out + NB + (size_t)NB * P1 * P2;           // [N,P1,P2]

    float* ws = (float*)d_ws;
    float* S      = ws;                                   // 4096
    float* xS     = S + DD * DD;                          // N*P1*D
    float* dx     = xS + (size_t)NB * P1 * DD;            // N*P1
    float* dy     = dx + NB * P1;                         // N*P2
    float* u      = dy + NB * P2;                         // N*P1
    float* v      = u + NB * P1;                          // N*P2
    float* errAcc = v + NB * P2;                          // ITER*ERRSLOTS
    int*   active = (int*)(errAcc + ITER * ERRSLOTS);     // 64 ints
    float* ws_end = (float*)(active + 64);

    // pm/ps: one (m,s) per column per iter block = 2 * NB*PCHUNKS*P2
    // floats = 8.4 MB. Prefer ws; fall back to the pi region (dead until
    // final_pass) if ws is too small. Branch is on a launch-constant.
    size_t base_floats = (size_t)(ws_end - ws);
    size_t pmps_floats = 2 * (size_t)NB * PCHUNKS * P2;
    float* pm;
    float* ps;
    if (ws_size >= (base_floats + pmps_floats) * sizeof(float)) {
        pm = ws_end;
        ps = ws_end + pmps_floats / 2;
    } else {
        pm = pi;
        ps = pi + pmps_floats / 2;
    }

    prep0<<<1, 256, 0, stream>>>(M, S, errAcc, active, cost);
    prep1<<<(NB * (P1 + P2)) / 4, 256, 0, stream>>>(x, y, S, xS, dx, dy, u, v);
    gemmC<<<dim3(P2 / 64, P1 / 64, NB), 256, 0, stream>>>(xS, y, dx, dy, C);
    // t = 0: unbounded q = -C -> max-safe slow path.
    iter_pass<<<NB * PCHUNKS, 256, 0, stream>>>(C, u, v, pm, ps, errAcc, active, 0);
    v_comb<<<NB * 32, 256, 0, stream>>>(pm, ps, v, errAcc, active, 0);
    // t >= 1: invariants bound all exp sums into fp32 range -> fast path.
    for (int t = 1; t < ITER; ++t) {
        iter_fast<<<NB * PCHUNKS, 512, 0, stream>>>(C, u, v, ps, errAcc, active, t);
        v_fast<<<NB * 32, 256, 0, stream>>>(ps, v, errAcc, active, t);
    }
    final_pass<<<NB * P1 / 16, 256, 0, stream>>>(C, u, v, pi, cost);
}

// Round 9
// 1031.774 us; speedup vs baseline: 2.0313x; 1.0126x over previous
//
#include <hip/hip_runtime.h>
#include <cstdint>
#include <cstddef>

// Problem constants (reference: N=4, P1=P2=2048, D=64, eps=0.1, 50 iters)
#define NB 4
#define P1 2048
#define P2 2048
#define DD 64
#define ITER 50
#define EPS 0.1f
#define INV_EPS 10.0f          // 1.0f/0.1f rounds to exactly 10.0f
#define THRESH 0.1f
// log(1/2048 + 1e-8) in fp32
#define LOG_MU -7.6245985f
#define ELOG (-0.76245985f)    // EPS * LOG_MU (== EPS * LOG_NU)
#define MU_VAL 0.00048829125f  // exp(LOG_MU) = 1/2048 + 1e-8
#define ERRSLOTS 32
#define RP (P2 / 4)            // float4s per row
#define PCHUNKS 128            // iter blocks per batch (16 rows each)

// ---------------------------------------------------------------------------
// prep0: S = M + M^T, zero err accumulators, init active flags, zero cost out
// ---------------------------------------------------------------------------
__global__ void prep0(const float* __restrict__ M, float* __restrict__ S,
                      float* __restrict__ errAcc, int* __restrict__ active,
                      float* __restrict__ cost) {
    int t = threadIdx.x;
    for (int k = t; k < DD * DD; k += 256) {
        int d = k >> 6, e = k & 63;
        S[k] = M[d * DD + e] + M[e * DD + d];
    }
    for (int k = t; k < ITER * ERRSLOTS; k += 256) errAcc[k] = 0.0f;
    if (t < 64) active[t] = (t == 0) ? 1 : 0;
    if (t < NB) cost[t] = 0.0f;
}

// ---------------------------------------------------------------------------
// prep1: one wave per row. x-rows: xS = x@S, dx = 0.5*x·(Sx), u=0.
//        y-rows: dy = 0.5*y·(Sy), v=0.
// ---------------------------------------------------------------------------
__global__ __launch_bounds__(256) void prep1(const float* __restrict__ x,
                                             const float* __restrict__ y,
                                             const float* __restrict__ S,
                                             float* __restrict__ xS,
                                             float* __restrict__ dx,
                                             float* __restrict__ dy,
                                             float* __restrict__ u,
                                             float* __restrict__ v) {
    __shared__ float Sl[DD * DD];
    int t = threadIdx.x;
    for (int k = t; k < DD * DD; k += 256) Sl[k] = S[k];
    __syncthreads();
    int wave = t >> 6, lane = t & 63;
    int r = blockIdx.x * 4 + wave;          // 0 .. N*(P1+P2)-1
    bool isX = r < NB * P1;
    const float* src = isX ? x : y;
    int rr = isX ? r : r - NB * P1;
    float xv = src[(size_t)rr * DD + lane];
    float acc = 0.0f;
    #pragma unroll
    for (int d = 0; d < DD; ++d) {
        float xd = __shfl(xv, d, 64);
        acc = fmaf(xd, Sl[d * DD + lane], acc);
    }
    float p = acc * xv;
    #pragma unroll
    for (int o = 32; o; o >>= 1) p += __shfl_xor(p, o, 64);
    if (isX) {
        xS[(size_t)rr * DD + lane] = acc;
        if (lane == 0) { dx[rr] = 0.5f * p; u[rr] = 0.0f; }
    } else {
        if (lane == 0) { dy[rr] = 0.5f * p; v[rr] = 0.0f; }
    }
}

// ---------------------------------------------------------------------------
// gemmC: C[n,i,j] = dx[n,i] + dy[n,j] - sum_e xS[n,i,e]*y[n,j,e]
// 64x64 tile per 256-thread block, 4x4 register tile per thread.
// ---------------------------------------------------------------------------
__global__ __launch_bounds__(256) void gemmC(const float* __restrict__ xS,
                                             const float* __restrict__ y,
                                             const float* __restrict__ dx,
                                             const float* __restrict__ dy,
                                             float* __restrict__ C) {
    __shared__ float xs[64][68];
    __shared__ float ys[64][68];
    int n = blockIdx.z;
    int i0 = blockIdx.y * 64, j0 = blockIdx.x * 64;
    int t = threadIdx.x;

    #pragma unroll
    for (int k = 0; k < 4; ++k) {
        int f = t + 256 * k;       // 0..1023
        int row = f >> 4;          // 0..63
        int c4 = f & 15;           // 0..15
        float4 a = ((const float4*)xS)[((size_t)(n * P1 + i0 + row)) * (DD / 4) + c4];
        xs[4 * c4 + 0][row] = a.x; xs[4 * c4 + 1][row] = a.y;
        xs[4 * c4 + 2][row] = a.z; xs[4 * c4 + 3][row] = a.w;
        float4 b = ((const float4*)y)[((size_t)(n * P2 + j0 + row)) * (DD / 4) + c4];
        ys[4 * c4 + 0][row] = b.x; ys[4 * c4 + 1][row] = b.y;
        ys[4 * c4 + 2][row] = b.z; ys[4 * c4 + 3][row] = b.w;
    }
    __syncthreads();

    int tx = t & 15, ty = t >> 4;
    float acc[4][4] = {};
    #pragma unroll
    for (int e = 0; e < 64; ++e) {
        float4 a = *(const float4*)&xs[e][4 * ty];
        float4 b = *(const float4*)&ys[e][4 * tx];
        acc[0][0] = fmaf(a.x, b.x, acc[0][0]); acc[0][1] = fmaf(a.x, b.y, acc[0][1]);
        acc[0][2] = fmaf(a.x, b.z, acc[0][2]); acc[0][3] = fmaf(a.x, b.w, acc[0][3]);
        acc[1][0] = fmaf(a.y, b.x, acc[1][0]); acc[1][1] = fmaf(a.y, b.y, acc[1][1]);
        acc[1][2] = fmaf(a.y, b.z, acc[1][2]); acc[1][3] = fmaf(a.y, b.w, acc[1][3]);
        acc[2][0] = fmaf(a.z, b.x, acc[2][0]); acc[2][1] = fmaf(a.z, b.y, acc[2][1]);
        acc[2][2] = fmaf(a.z, b.z, acc[2][2]); acc[2][3] = fmaf(a.z, b.w, acc[2][3]);
        acc[3][0] = fmaf(a.w, b.x, acc[3][0]); acc[3][1] = fmaf(a.w, b.y, acc[3][1]);
        acc[3][2] = fmaf(a.w, b.z, acc[3][2]); acc[3][3] = fmaf(a.w, b.w, acc[3][3]);
    }

    int iBase = i0 + ty * 4, jBase = j0 + tx * 4;
    float4 dy4 = *(const float4*)&dy[n * P2 + jBase];
    #pragma unroll
    for (int r = 0; r < 4; ++r) {
        float dxv = dx[n * P1 + iBase + r];
        float4 o;
        o.x = dxv + dy4.x - acc[r][0];
        o.y = dxv + dy4.y - acc[r][1];
        o.z = dxv + dy4.z - acc[r][2];
        o.w = dxv + dy4.w - acc[r][3];
        *(float4*)&C[((size_t)(n * P1 + iBase + r)) * P2 + jBase] = o;
    }
}

// ---------------------------------------------------------------------------
// Row helpers (r4-validated)
// ---------------------------------------------------------------------------
__device__ __forceinline__ void load_row8(float4 dst[8], const float4* base, int lane) {
    #pragma unroll
    for (int k = 0; k < 8; ++k) dst[k] = base[lane + 64 * k];
}

// Transforms c in place to q = (ai - C) + b; returns eps*LSE_j(q_j/eps).
__device__ __forceinline__ float row_lse(float4 c[8], float ai, const float* bl, int lane) {
    float m = -3.4e38f;
    #pragma unroll
    for (int k = 0; k < 8; ++k) {
        float4 vv = ((const float4*)bl)[lane + 64 * k];
        c[k].x = (ai - c[k].x) + vv.x;
        c[k].y = (ai - c[k].y) + vv.y;
        c[k].z = (ai - c[k].z) + vv.z;
        c[k].w = (ai - c[k].w) + vv.w;
        m = fmaxf(m, fmaxf(fmaxf(c[k].x, c[k].y), fmaxf(c[k].z, c[k].w)));
    }
    #pragma unroll
    for (int o = 1; o < 64; o <<= 1) m = fmaxf(m, __shfl_xor(m, o, 64));
    float s = 0.0f;
    #pragma unroll
    for (int k = 0; k < 8; ++k)
        s += __expf((c[k].x - m) * INV_EPS) + __expf((c[k].y - m) * INV_EPS) +
             __expf((c[k].z - m) * INV_EPS) + __expf((c[k].w - m) * INV_EPS);
    #pragma unroll
    for (int o = 1; o < 64; o <<= 1) s += __shfl_xor(s, o, 64);
    return EPS * __logf(s) + m;
}

// Online (m,s) merge of one scalar term q (values in C-units, exp scaled by 1/eps)
__device__ __forceinline__ void mergec(float& m, float& s, float q) {
    float nm = fmaxf(m, q);
    s = s * __expf((m - nm) * INV_EPS) + __expf((q - nm) * INV_EPS);
    m = nm;
}
__device__ __forceinline__ void mergems(float& m, float& s, float mo, float so) {
    float nm = fmaxf(m, mo);
    s = s * __expf((m - nm) * INV_EPS) + so * __expf((mo - nm) * INV_EPS);
    m = nm;
}
__device__ __forceinline__ void merge44(float4& m, float4& s, float4 mo, float4 so) {
    mergems(m.x, s.x, mo.x, so.x);
    mergems(m.y, s.y, mo.y, so.y);
    mergems(m.z, s.z, mo.z, so.z);
    mergems(m.w, s.w, mo.w, so.w);
}

// Merge row's q (+wave-uniform dr = u_new - u_old) into per-column (M,S) regs.
__device__ __forceinline__ void merge_row(float4 M[8], float4 S[8],
                                          const float4 q[8], float dr) {
    #pragma unroll
    for (int k = 0; k < 8; ++k) {
        mergec(M[k].x, S[k].x, q[k].x + dr);
        mergec(M[k].y, S[k].y, q[k].y + dr);
        mergec(M[k].z, S[k].z, q[k].z + dr);
        mergec(M[k].w, S[k].w, q[k].w + dr);
    }
}

// ---------------------------------------------------------------------------
// iter_pass (max-safe, t=0 only — q=-C unbounded): full Sinkhorn u-update
// plus in-register per-column (m,s) partials. 16 rows/block, 512 blocks.
// ---------------------------------------------------------------------------
__global__ __launch_bounds__(256) void iter_pass(const float* __restrict__ C,
                                                 float* __restrict__ u,
                                                 const float* __restrict__ v,
                                                 float* __restrict__ pm,
                                                 float* __restrict__ ps,
                                                 float* __restrict__ errAcc,
                                                 const int* __restrict__ active,
                                                 int t_iter) {
    if (!active[t_iter]) return;
    __shared__ float bl[P2];          // 8 KB: v values for this batch
    __shared__ float4 LM[4][512];     // 32 KB: per-wave column maxima
    __shared__ float4 LS[4][512];     // 32 KB: per-wave column sums
    __shared__ float da_s[4];
    int t = threadIdx.x;
    int n = blockIdx.x >> 7;                       // PCHUNKS=128 blocks/batch
    int i0 = (blockIdx.x & (PCHUNKS - 1)) * 16;
    {
        const float4* bsrc = (const float4*)(v + n * P2);
        ((float4*)bl)[t] = bsrc[t];
        ((float4*)bl)[t + 256] = bsrc[t + 256];
    }
    __syncthreads();

    int wave = t >> 6, lane = t & 63;
    int irow = i0 + wave * 4;
    float* arow = u + n * P1 + irow;
    float a0 = arow[0], a1 = arow[1], a2 = arow[2], a3 = arow[3];
    const float4* base = (const float4*)(C + ((size_t)(n * P1 + irow)) * P2);

    float4 M[8], S[8];
    #pragma unroll
    for (int k = 0; k < 8; ++k) {
        M[k] = make_float4(-3.4e38f, -3.4e38f, -3.4e38f, -3.4e38f);
        S[k] = make_float4(0.0f, 0.0f, 0.0f, 0.0f);
    }

    float4 A[8], B[8];
    load_row8(A, base, lane);
    load_row8(B, base + RP, lane);
    float l0 = row_lse(A, a0, bl, lane);
    float d0 = ELOG - l0;
    merge_row(M, S, A, d0);
    load_row8(A, base + 2 * RP, lane);
    float l1 = row_lse(B, a1, bl, lane);
    float d1 = ELOG - l1;
    merge_row(M, S, B, d1);
    load_row8(B, base + 3 * RP, lane);
    float l2 = row_lse(A, a2, bl, lane);
    float d2 = ELOG - l2;
    merge_row(M, S, A, d2);
    float l3 = row_lse(B, a3, bl, lane);
    float d3 = ELOG - l3;
    merge_row(M, S, B, d3);

    if (lane == 0) {
        arow[0] = a0 + d0; arow[1] = a1 + d1;
        arow[2] = a2 + d2; arow[3] = a3 + d3;
        da_s[wave] = fabsf(d0) + fabsf(d1) + fabsf(d2) + fabsf(d3);
    }

    // cross-wave column merge through LDS
    #pragma unroll
    for (int k = 0; k < 8; ++k) {
        LM[wave][lane + 64 * k] = M[k];
        LS[wave][lane + 64 * k] = S[k];
    }
    __syncthreads();

    float4* pm4 = (float4*)pm;
    float4* ps4 = (float4*)ps;
    size_t pb4 = (size_t)blockIdx.x * 512;
    #pragma unroll
    for (int sl = 0; sl < 2; ++sl) {
        int slot = t + 256 * sl;
        float4 m = LM[0][slot], s = LS[0][slot];
        merge44(m, s, LM[1][slot], LS[1][slot]);
        merge44(m, s, LM[2][slot], LS[2][slot]);
        merge44(m, s, LM[3][slot], LS[3][slot]);
        pm4[pb4 + slot] = m;
        ps4[pb4 + slot] = s;
    }

    if (t == 0) {
        atomicAdd(&errAcc[t_iter * ERRSLOTS + (blockIdx.x & (ERRSLOTS - 1))],
                  da_s[0] + da_s[1] + da_s[2] + da_s[3]);
    }
}

// ---------------------------------------------------------------------------
// v_comb (t=0 only): merge PCHUNKS (m,s) partials per column, apply v update,
// advance active.
// ---------------------------------------------------------------------------
__global__ __launch_bounds__(256) void v_comb(const float* __restrict__ pm,
                                              const float* __restrict__ ps,
                                              float* __restrict__ v,
                                              const float* __restrict__ errAcc,
                                              int* __restrict__ active,
                                              int t_iter) {
    if (blockIdx.x == 0 && threadIdx.x == 0) {
        float e = 0.0f;
        #pragma unroll
        for (int q = 0; q < ERRSLOTS; ++q) e += errAcc[t_iter * ERRSLOTS + q];
        if (active[t_iter] && (e * 0.25f >= THRESH)) active[t_iter + 1] = 1;
    }
    if (!active[t_iter]) return;
    __shared__ float LMv[4][64];
    __shared__ float LSv[4][64];
    int t = threadIdx.x, wave = t >> 6, lane = t & 63;
    int n = blockIdx.x >> 5;
    int j = ((blockIdx.x & 31) << 6) + lane;
    const float* pmb = pm + ((size_t)(n * PCHUNKS + wave * 32)) * P2 + j;
    const float* psb = ps + ((size_t)(n * PCHUNKS + wave * 32)) * P2 + j;
    float m0 = -3.4e38f, s0 = 0.0f, m1 = -3.4e38f, s1 = 0.0f;
    float m2 = -3.4e38f, s2 = 0.0f, m3 = -3.4e38f, s3 = 0.0f;
    #pragma unroll
    for (int c = 0; c < 32; c += 4) {
        mergems(m0, s0, pmb[(size_t)(c + 0) * P2], psb[(size_t)(c + 0) * P2]);
        mergems(m1, s1, pmb[(size_t)(c + 1) * P2], psb[(size_t)(c + 1) * P2]);
        mergems(m2, s2, pmb[(size_t)(c + 2) * P2], psb[(size_t)(c + 2) * P2]);
        mergems(m3, s3, pmb[(size_t)(c + 3) * P2], psb[(size_t)(c + 3) * P2]);
    }
    mergems(m0, s0, m1, s1);
    mergems(m2, s2, m3, s3);
    mergems(m0, s0, m2, s2);
    LMv[wave][lane] = m0; LSv[wave][lane] = s0;
    __syncthreads();
    if (wave == 0) {
        float m = LMv[0][lane], s = LSv[0][lane];
        mergems(m, s, LMv[1][lane], LSv[1][lane]);
        mergems(m, s, LMv[2][lane], LSv[2][lane]);
        mergems(m, s, LMv[3][lane], LSv[3][lane]);
        float lse = EPS * __logf(s) + m;
        v[n * P2 + j] = v[n * P2 + j] + ELOG - lse;
    }
}

// ---------------------------------------------------------------------------
// FAST PATH (t >= 1). Invariant (r5-validated): after iteration 0's full
// (u,v) update, every exp((u-C+v)/eps) <= MU and row/col sums live in
// [2.4e-7, 4.4e6] -> plain fp32 sums, no max tracking. u,v stay in the
// LOG domain (the r2 multiplicative-tilt path accumulated drift and NaN'd).
// ---------------------------------------------------------------------------
__device__ __forceinline__ float row_sum(float4 c[8], float aiv, const float* bl,
                                         int lane) {
    float s = 0.0f;
    #pragma unroll
    for (int k = 0; k < 8; ++k) {
        float4 vv = ((const float4*)bl)[lane + 64 * k];
        c[k].x = __expf(fmaf(c[k].x, -INV_EPS, aiv + vv.x));
        c[k].y = __expf(fmaf(c[k].y, -INV_EPS, aiv + vv.y));
        c[k].z = __expf(fmaf(c[k].z, -INV_EPS, aiv + vv.z));
        c[k].w = __expf(fmaf(c[k].w, -INV_EPS, aiv + vv.w));
        s += (c[k].x + c[k].y) + (c[k].z + c[k].w);
    }
    #pragma unroll
    for (int o = 1; o < 64; o <<= 1) s += __shfl_xor(s, o, 64);
    return s;
}

__device__ __forceinline__ void acc_row(float4 S[8], const float4 q[8], float ed) {
    #pragma unroll
    for (int k = 0; k < 8; ++k) {
        S[k].x = fmaf(q[k].x, ed, S[k].x);
        S[k].y = fmaf(q[k].y, ed, S[k].y);
        S[k].z = fmaf(q[k].z, ed, S[k].z);
        S[k].w = fmaf(q[k].w, ed, S[k].w);
    }
}

// iter_fast (r7-validated, 1045 us): 16 rows/block, 512 blocks, 512 threads
// = 8 waves/block, 2 rows/wave. LDS 72KB -> 2 blocks/CU, 16 waves/CU.
__global__ __launch_bounds__(512) void iter_fast(const float* __restrict__ C,
                                                 float* __restrict__ u,
                                                 const float* __restrict__ v,
                                                 float* __restrict__ ps,
                                                 float* __restrict__ errAcc,
                                                 const int* __restrict__ active,
                                                 int t_iter) {
    if (!active[t_iter]) return;
    __shared__ float bl[P2];          // 8 KB: v*INV_EPS for this batch
    __shared__ float4 LS[8][512];     // 64 KB: per-wave column sums
    __shared__ float da_s[8];
    int t = threadIdx.x;              // 0..511
    int n = blockIdx.x >> 7;
    int i0 = (blockIdx.x & (PCHUNKS - 1)) * 16;
    {
        const float4* bsrc = (const float4*)(v + n * P2);
        float4 b0 = bsrc[t];
        b0.x *= INV_EPS; b0.y *= INV_EPS; b0.z *= INV_EPS; b0.w *= INV_EPS;
        ((float4*)bl)[t] = b0;
    }
    __syncthreads();

    int wave = t >> 6, lane = t & 63;
    int irow = i0 + wave * 2;
    float* arow = u + n * P1 + irow;
    float a0 = arow[0], a1 = arow[1];
    const float4* base = (const float4*)(C + ((size_t)(n * P1 + irow)) * P2);

    float4 S[8];
    #pragma unroll
    for (int k = 0; k < 8; ++k) S[k] = make_float4(0.0f, 0.0f, 0.0f, 0.0f);

    float4 X[8], Y[8];
    load_row8(X, base, lane);          // row 0
    load_row8(Y, base + RP, lane);     // row 1 in flight during row 0 compute
    float s0 = row_sum(X, a0 * INV_EPS, bl, lane);
    float d0 = ELOG - EPS * __logf(s0);
    acc_row(S, X, __fdividef(MU_VAL, s0));
    float s1 = row_sum(Y, a1 * INV_EPS, bl, lane);
    float d1 = ELOG - EPS * __logf(s1);
    acc_row(S, Y, __fdividef(MU_VAL, s1));

    if (lane == 0) {
        arow[0] = a0 + d0; arow[1] = a1 + d1;
        da_s[wave] = fabsf(d0) + fabsf(d1);
    }

    // cross-wave column sum through LDS (plain adds)
    #pragma unroll
    for (int k = 0; k < 8; ++k) LS[wave][lane + 64 * k] = S[k];
    __syncthreads();

    float4* ps4 = (float4*)ps;
    size_t pb4 = (size_t)blockIdx.x * 512;
    {
        int slot = t;                  // 512 threads cover all 512 slots
        float4 x0 = LS[0][slot], x1 = LS[1][slot];
        float4 x2 = LS[2][slot], x3 = LS[3][slot];
        float4 x4 = LS[4][slot], x5 = LS[5][slot];
        float4 x6 = LS[6][slot], x7 = LS[7][slot];
        float4 o;
        o.x = ((x0.x + x1.x) + (x2.x + x3.x)) + ((x4.x + x5.x) + (x6.x + x7.x));
        o.y = ((x0.y + x1.y) + (x2.y + x3.y)) + ((x4.y + x5.y) + (x6.y + x7.y));
        o.z = ((x0.z + x1.z) + (x2.z + x3.z)) + ((x4.z + x5.z) + (x6.z + x7.z));
        o.w = ((x0.w + x1.w) + (x2.w + x3.w)) + ((x4.w + x5.w) + (x6.w + x7.w));
        ps4[pb4 + slot] = o;
    }

    if (t == 0) {
        atomicAdd(&errAcc[t_iter * ERRSLOTS + (blockIdx.x & (ERRSLOTS - 1))],
                  ((da_s[0] + da_s[1]) + (da_s[2] + da_s[3])) +
                  ((da_s[4] + da_s[5]) + (da_s[6] + da_s[7])));
    }
}

// v_fast: plain-sum merge of PCHUNKS=128 partials per column, v update,
// advance active. 128 blocks; wave w merges chunks [32w, 32w+32).
__global__ __launch_bounds__(256) void v_fast(const float* __restrict__ ps,
                                              float* __restrict__ v,
                                              const float* __restrict__ errAcc,
                                              int* __restrict__ active,
                                              int t_iter) {
    if (blockIdx.x == 0 && threadIdx.x == 0) {
        float e = 0.0f;
        #pragma unroll
        for (int q = 0; q < ERRSLOTS; ++q) e += errAcc[t_iter * ERRSLOTS + q];
        if (active[t_iter] && (e * 0.25f >= THRESH)) active[t_iter + 1] = 1;
    }
    if (!active[t_iter]) return;
    __shared__ float LSv[4][64];
    int t = threadIdx.x, wave = t >> 6, lane = t & 63;
    int n = blockIdx.x >> 5;
    int j = ((blockIdx.x & 31) << 6) + lane;
    const float* psb = ps + ((size_t)(n * PCHUNKS + wave * 32)) * P2 + j;
    float s0 = 0.0f, s1 = 0.0f, s2 = 0.0f, s3 = 0.0f;
    #pragma unroll
    for (int c = 0; c < 32; c += 4) {
        s0 += psb[(size_t)(c + 0) * P2];
        s1 += psb[(size_t)(c + 1) * P2];
        s2 += psb[(size_t)(c + 2) * P2];
        s3 += psb[(size_t)(c + 3) * P2];
    }
    LSv[wave][lane] = (s0 + s1) + (s2 + s3);
    __syncthreads();
    if (wave == 0) {
        float s = (LSv[0][lane] + LSv[1][lane]) + (LSv[2][lane] + LSv[3][lane]);
        v[n * P2 + j] = v[n * P2 + j] + ELOG - EPS * __logf(s);
    }
}

// ---------------------------------------------------------------------------
// final_pass: pi = exp((u_i - C + v_j)/eps), cost_n = sum(pi*C).
// CHANGE vs r7 (the only change this round): 512 threads = 8 waves/block,
// 2 rows/wave, same 512-block grid and per-block work — the exact transform
// that took iter_fast from 8 to 16 waves/CU (+55 us total in r7). LDS 8KB
// v-tile + red[8]; arithmetic and memory layout identical.
// ---------------------------------------------------------------------------
__device__ __forceinline__ float row_pi(const float4 c[8], float ui, const float* vl,
                                        int lane, float4* prow) {
    float acc = 0.0f;
    #pragma unroll
    for (int k = 0; k < 8; ++k) {
        float4 vv = ((const float4*)vl)[lane + 64 * k];
        float4 p;
        p.x = __expf(((ui - c[k].x) + vv.x) * INV_EPS);
        p.y = __expf(((ui - c[k].y) + vv.y) * INV_EPS);
        p.z = __expf(((ui - c[k].z) + vv.z) * INV_EPS);
        p.w = __expf(((ui - c[k].w) + vv.w) * INV_EPS);
        prow[lane + 64 * k] = p;
        acc += p.x * c[k].x + p.y * c[k].y + p.z * c[k].z + p.w * c[k].w;
    }
    return acc;
}

__global__ __launch_bounds__(512) void final_pass(const float* __restrict__ C,
                                                  const float* __restrict__ u,
                                                  const float* __restrict__ v,
                                                  float* __restrict__ pi,
                                                  float* __restrict__ cost) {
    __shared__ float vl[P2];
    __shared__ float red[8];
    int t = threadIdx.x;              // 0..511
    int n = blockIdx.x >> 7;
    int i0 = (blockIdx.x & 127) * 16;
    {
        const float4* vsrc = (const float4*)(v + n * P2);
        ((float4*)vl)[t] = vsrc[t];
    }
    __syncthreads();

    int wave = t >> 6, lane = t & 63;
    int irow = i0 + wave * 2;
    const float* urow = u + n * P1 + irow;
    float u0 = urow[0], u1 = urow[1];
    const float4* base = (const float4*)(C + ((size_t)(n * P1 + irow)) * P2);
    float4* pbase = (float4*)(pi + ((size_t)(n * P1 + irow)) * P2);

    float4 A[8], B[8];
    load_row8(A, base, lane);
    load_row8(B, base + RP, lane);
    float acc = row_pi(A, u0, vl, lane, pbase);
    acc += row_pi(B, u1, vl, lane, pbase + RP);

    #pragma unroll
    for (int o = 1; o < 64; o <<= 1) acc += __shfl_xor(acc, o, 64);
    if (lane == 0) red[wave] = acc;
    __syncthreads();
    if (t == 0) {
        atomicAdd(&cost[n], ((red[0] + red[1]) + (red[2] + red[3])) +
                            ((red[4] + red[5]) + (red[6] + red[7])));
    }
}

// ---------------------------------------------------------------------------
extern "C" void kernel_launch(void* const* d_in, const int* in_sizes, int n_in,
                              void* d_out, int out_size, void* d_ws, size_t ws_size,
                              hipStream_t stream) {
    const float* x = (const float*)d_in[0];   // [N,P1,D]
    const float* y = (const float*)d_in[1];   // [N,P2,D]
    const float* M = (const float*)d_in[2];   // [D,D]
    float* out = (float*)d_out;
    float* cost = out;                                    // [N]
    float* pi = out + NB;                                 // [N,P1,P2]
    float* C = out + NB + (size_t)NB * P1 * P2;           // [N,P1,P2]

    float* ws = (float*)d_ws;
    float* S      = ws;                                   // 4096
    float* xS     = S + DD * DD;                          // N*P1*D
    float* dx     = xS + (size_t)NB * P1 * DD;            // N*P1
    float* dy     = dx + NB * P1;                         // N*P2
    float* u      = dy + NB * P2;                         // N*P1
    float* v      = u + NB * P1;                          // N*P2
    float* errAcc = v + NB * P2;                          // ITER*ERRSLOTS
    int*   active = (int*)(errAcc + ITER * ERRSLOTS);     // 64 ints
    float* ws_end = (float*)(active + 64);

    // pm/ps: one (m,s) per column per iter block = 2 * NB*PCHUNKS*P2
    // floats = 8.4 MB. Prefer ws; fall back to the pi region (dead until
    // final_pass) if ws is too small. Branch is on a launch-constant.
    size_t base_floats = (size_t)(ws_end - ws);
    size_t pmps_floats = 2 * (size_t)NB * PCHUNKS * P2;
    float* pm;
    float* ps;
    if (ws_size >= (base_floats + pmps_floats) * sizeof(float)) {
        pm = ws_end;
        ps = ws_end + pmps_floats / 2;
    } else {
        pm = pi;
        ps = pi + pmps_floats / 2;
    }

    prep0<<<1, 256, 0, stream>>>(M, S, errAcc, active, cost);
    prep1<<<(NB * (P1 + P2)) / 4, 256, 0, stream>>>(x, y, S, xS, dx, dy, u, v);
    gemmC<<<dim3(P2 / 64, P1 / 64, NB), 256, 0, stream>>>(xS, y, dx, dy, C);
    // t = 0: unbounded q = -C -> max-safe slow path.
    iter_pass<<<NB * PCHUNKS, 256, 0, stream>>>(C, u, v, pm, ps, errAcc, active, 0);
    v_comb<<<NB * 32, 256, 0, stream>>>(pm, ps, v, errAcc, active, 0);
    // t >= 1: invariants bound all exp sums into fp32 range -> fast path.
    for (int t = 1; t < ITER; ++t) {
        iter_fast<<<NB * PCHUNKS, 512, 0, stream>>>(C, u, v, ps, errAcc, active, t);
        v_fast<<<NB * 32, 256, 0, stream>>>(ps, v, errAcc, active, t);
    }
    final_pass<<<NB * P1 / 16, 512, 0, stream>>>(C, u, v, pi, cost);
}